// Round 11
// baseline (4918.873 us; speedup 1.0000x reference)
//
#include <hip/hip_runtime.h>
#include <hip/hip_bf16.h>
#include <math.h>

typedef __attribute__((ext_vector_type(8))) short bf16x8;
typedef __attribute__((ext_vector_type(4))) float f32x4;
typedef __attribute__((ext_vector_type(4))) unsigned int u32x4;
typedef __attribute__((ext_vector_type(2))) unsigned int u32x2;

#define TT 1024
#define BB 128
#define II 256
#define SS 512
#define OUT_T 1025
#define OUT_BSTRIDE ((size_t)OUT_T * SS)   // 524800

// ---------- bf16 helpers ----------
static __device__ __forceinline__ unsigned short f2bf(float f) {
  union { float f; unsigned int u; } v; v.f = f;
  unsigned int r = v.u + 0x7fffu + ((v.u >> 16) & 1u);
  return (unsigned short)(r >> 16);
}
static __device__ __forceinline__ float bf2f(unsigned short h) {
  union { unsigned int u; float f; } v; v.u = ((unsigned int)h) << 16;
  return v.f;
}
static __device__ __forceinline__ bf16x8 pack8(const float* p) {
  float4 a = *(const float4*)p;
  float4 b = *(const float4*)(p + 4);
  bf16x8 r;
  r[0]=(short)f2bf(a.x); r[1]=(short)f2bf(a.y); r[2]=(short)f2bf(a.z); r[3]=(short)f2bf(a.w);
  r[4]=(short)f2bf(b.x); r[5]=(short)f2bf(b.y); r[6]=(short)f2bf(b.z); r[7]=(short)f2bf(b.w);
  return r;
}
static __device__ __forceinline__ float bfat(u32x2 v, int q) {
  unsigned int u = (q < 2) ? v[0] : v[1];
  u = (q & 1) ? (u >> 16) : (u & 0xffffu);
  return bf2f((unsigned short)u);
}
// tanh via exp2; clamp avoids inf/inf
static __device__ __forceinline__ float fast_tanh(float x) {
  float x2 = fminf(x * 2.8853900817779268f, 88.0f);
  float e = __builtin_amdgcn_exp2f(x2);
  return (e - 1.0f) * __builtin_amdgcn_rcpf(e + 1.0f);
}

// ---------- device-coherent publish (LLC scope; proven) ----------
static __device__ __forceinline__ void st_coh_b128(void* p, u32x4 v) {
  asm volatile("global_store_dwordx4 %0, %1, off sc0 sc1" :: "v"(p), "v"(v) : "memory");
}

// ---------- SAFE batched acquire: 8 loads + waitcnt in ONE asm block ----
// (outputs valid at asm end; no compiler copy can observe in-flight regs)
static __device__ __forceinline__ void mega_acq(const char* an,
    u32x4& v0, u32x4& v1, u32x4& v2, u32x4& v3,
    u32x4& v4, u32x4& v5, u32x4& v6, u32x4& v7) {
  asm volatile(
    "global_load_dwordx4 %0, %8, off sc0 sc1\n\t"
    "global_load_dwordx4 %1, %8, off offset:256 sc0 sc1\n\t"
    "global_load_dwordx4 %2, %8, off offset:512 sc0 sc1\n\t"
    "global_load_dwordx4 %3, %8, off offset:768 sc0 sc1\n\t"
    "global_load_dwordx4 %4, %8, off offset:1024 sc0 sc1\n\t"
    "global_load_dwordx4 %5, %8, off offset:1280 sc0 sc1\n\t"
    "global_load_dwordx4 %6, %8, off offset:1536 sc0 sc1\n\t"
    "global_load_dwordx4 %7, %8, off offset:1792 sc0 sc1\n\t"
    "s_waitcnt vmcnt(0)"
    : "=&v"(v0), "=&v"(v1), "=&v"(v2), "=&v"(v3),
      "=&v"(v4), "=&v"(v5), "=&v"(v6), "=&v"(v7)
    : "v"(an) : "memory");
  __builtin_amdgcn_sched_barrier(0);
}
// 1 if any of the 4 words' low-16 epoch != expd
static __device__ __forceinline__ unsigned chk4(u32x4 v, unsigned expd) {
  return ((((v[0] ^ expd) | (v[1] ^ expd) | (v[2] ^ expd) | (v[3] ^ expd)) & 0xffffu) != 0u) ? 1u : 0u;
}

// =====================================================================
// Phase 1: projections (proven). proj[t][b][1536] bf16:
// [0:512)=x@B0w^T+b0, [512:1024)=x@B1w^T+b1, [1024:1536)=sigmoid(x@Gw^T+gb)
// =====================================================================
__global__ __launch_bounds__(256) void proj_kernel(
    const float* __restrict__ x,
    const float* __restrict__ B0w, const float* __restrict__ B0b,
    const float* __restrict__ B1w, const float* __restrict__ B1b,
    const float* __restrict__ Gw,  const float* __restrict__ Gb,
    unsigned short* __restrict__ proj)
{
  __shared__ unsigned short Xs[64 * 264];
  __shared__ unsigned short Ws[64 * 40];

  int m0 = blockIdx.x * 64;
  int tid = threadIdx.x, lane = tid & 63, wid = tid >> 6;
  int lane15 = lane & 15, kslot = lane >> 4;
  int mt0 = (wid >> 1) * 2, nt0 = (wid & 1) * 2;
  int sr = tid >> 2, sc = tid & 3;

#pragma unroll
  for (int it = 0; it < 8; ++it) {
    int task = tid + 256 * it; int r = task >> 5, c = task & 31;
    *(bf16x8*)&Xs[r * 264 + c * 8] = pack8(x + (size_t)(m0 + r) * II + c * 8);
  }
  __syncthreads();

  for (int nt = 0; nt < 24; ++nt) {
    int n0 = nt * 64;
    const float* Wp; const float* bp; bool isgate = false;
    if (n0 < 512)       { Wp = B0w + (size_t)n0 * II;          bp = B0b + n0; }
    else if (n0 < 1024) { Wp = B1w + (size_t)(n0 - 512) * II;  bp = B1b + (n0 - 512); }
    else                { Wp = Gw  + (size_t)(n0 - 1024) * II; bp = Gb + (n0 - 1024); isgate = true; }

    f32x4 acc[2][2] = {};
    for (int k0 = 0; k0 < II; k0 += 32) {
      __syncthreads();
      *(bf16x8*)&Ws[sr * 40 + sc * 8] = pack8(Wp + (size_t)sr * II + k0 + sc * 8);
      __syncthreads();
      bf16x8 af[2], bf[2];
#pragma unroll
      for (int mi = 0; mi < 2; ++mi)
        af[mi] = *(const bf16x8*)&Xs[((mt0 + mi) * 16 + lane15) * 264 + k0 + 8 * kslot];
#pragma unroll
      for (int ni = 0; ni < 2; ++ni)
        bf[ni] = *(const bf16x8*)&Ws[((nt0 + ni) * 16 + lane15) * 40 + 8 * kslot];
#pragma unroll
      for (int mi = 0; mi < 2; ++mi)
#pragma unroll
        for (int ni = 0; ni < 2; ++ni)
          acc[mi][ni] = __builtin_amdgcn_mfma_f32_16x16x32_bf16(af[mi], bf[ni], acc[mi][ni], 0, 0, 0);
    }
#pragma unroll
    for (int mi = 0; mi < 2; ++mi)
#pragma unroll
      for (int ni = 0; ni < 2; ++ni)
#pragma unroll
        for (int q = 0; q < 4; ++q) {
          int m  = m0 + (mt0 + mi) * 16 + kslot * 4 + q;
          int nl = (nt0 + ni) * 16 + lane15;
          int b = m >> 10, t = m & 1023;              // m = b*T + t
          float v = acc[mi][ni][q] + bp[nl];
          if (isgate) v = 1.0f / (1.0f + expf(-v));
          proj[((size_t)t * BB + b) * 1536 + n0 + nl] = f2bf(v);
        }
  }
}

// =====================================================================
// Phase 2: recurrence, TWO chains per block. 32 blocks = 4 group-pairs
// (gg=bid&3) x 8 col-slices (j=bid>>2). Chain A rows gg*32..+15, chain B
// rows gg*32+16..+31; both share the block's 64-col A-fragments.
// Per iteration: [acqA|MFMA A|ew A|pubA|outA/projA][acqB|MFMA B|...] —
// each chain's LLC RT is a single clean mega-acquire (data published a
// full iteration earlier -> no retries), and chain A's out/proj traffic
// overlaps chain B's acquire wait. No drains, no flags (epoch protocol).
// =====================================================================
__global__ __launch_bounds__(256, 1) void recur_kernel(
    const float* __restrict__ s0,
    const float* __restrict__ A0w, const float* __restrict__ A1w,
    const unsigned short* __restrict__ proj,
    const float* __restrict__ alpha_p, const int* __restrict__ z_p,
    unsigned int* state32,             // [2][128][512] epoch-stamped words
    float* __restrict__ out)           // [128][1025][512]
{
  __shared__ unsigned short SbufA[16 * 520];
  __shared__ unsigned short SbufB[16 * 520];

  int tid = threadIdx.x, lane = tid & 63, wid = tid >> 6;   // 4 waves
  int gg = blockIdx.x & 3, j = blockIdx.x >> 2;
  int bA = gg * 32, bB = gg * 32 + 16;
  int c0 = j * 64;
  int lane15 = lane & 15, kslot = lane >> 4;
  int colA = c0 + wid * 16 + lane15;        // A-fragment col
  int ccb  = c0 + wid * 16 + kslot * 4;     // lane's 4 output cols
  int rowA = bA + lane15, rowB = bB + lane15;
  int prow = tid >> 4, pch = tid & 15;      // acquire map: row, 16B chunk
  float alpha = *alpha_p; int z = *z_p; float om_a = 1.0f - alpha;

  // ---- A0/A1 fragments in registers (compile-time indices only) ----
  bf16x8 Af0[16], Af1[16];
#pragma unroll
  for (int kk = 0; kk < 16; ++kk) {
    int k0 = kk * 32 + kslot * 8;
    Af0[kk] = pack8(A0w + (size_t)colA * SS + k0);
    Af1[kk] = pack8(A1w + (size_t)colA * SS + k0);
  }

  // ---- stage s0 tiles; out[:,0,:] (j==0, 32 rows); carries; proj t=0 ----
#pragma unroll
  for (int c2 = 0; c2 < 4; ++c2) {
    int e = tid + 256 * c2; int rr = e >> 6, kc = e & 63;
    *(bf16x8*)&SbufA[rr * 520 + kc * 8] = pack8(s0 + (size_t)(bA + rr) * SS + kc * 8);
    *(bf16x8*)&SbufB[rr * 520 + kc * 8] = pack8(s0 + (size_t)(bB + rr) * SS + kc * 8);
  }
  if (j == 0) {
#pragma unroll
    for (int it = 0; it < 16; ++it) {
      int task = tid + 256 * it;             // 32 rows x 128 float4
      int rr = task >> 7, f4 = task & 127;
      *(float4*)(out + (size_t)(bA + rr) * OUT_BSTRIDE + f4 * 4) =
          *(const float4*)(s0 + (size_t)(bA + rr) * SS + f4 * 4);
    }
  }
  float4 sA4 = *(const float4*)(s0 + (size_t)rowA * SS + ccb);
  float4 sB4 = *(const float4*)(s0 + (size_t)rowB * SS + ccb);
  float sprevA[4] = {sA4.x, sA4.y, sA4.z, sA4.w};
  float sprevB[4] = {sB4.x, sB4.y, sB4.z, sB4.w};

  const unsigned short* ppA = proj + (size_t)rowA * 1536 + ccb;
  const unsigned short* ppB = proj + (size_t)rowB * 1536 + ccb;
  u32x2 pA0 = *(const u32x2*)(ppA), pA1 = *(const u32x2*)(ppA + 512), pAg = *(const u32x2*)(ppA + 1024);
  u32x2 pB0 = *(const u32x2*)(ppB), pB1 = *(const u32x2*)(ppB + 512), pBg = *(const u32x2*)(ppB + 1024);

  // named pointers (rule #20)
  unsigned int* pubA0 = state32 + (size_t)rowA * SS + ccb;
  unsigned int* pubA1 = pubA0 + (size_t)BB * SS;
  unsigned int* pubB0 = state32 + (size_t)rowB * SS + ccb;
  unsigned int* pubB1 = pubB0 + (size_t)BB * SS;
  const char* acqA0 = (const char*)(state32 + (size_t)(bA + prow) * SS) + pch * 16;
  const char* acqA1 = acqA0 + (size_t)BB * SS * 4;
  const char* acqB0 = (const char*)(state32 + (size_t)(bB + prow) * SS) + pch * 16;
  const char* acqB1 = acqB0 + (size_t)BB * SS * 4;
  float* outA = out + (size_t)rowA * OUT_BSTRIDE + ccb;
  float* outB = out + (size_t)rowB * OUT_BSTRIDE + ccb;

  __syncthreads();

#define LANDALL(SL, V0,V1,V2,V3,V4,V5,V6,V7) do {                      \
    unsigned short* sl_ = (SL) + prow * 520 + pch * 4;                 \
    u32x2 dd_;                                                         \
    dd_[0] = ((V0)[0] >> 16) | ((V0)[1] & 0xffff0000u);                \
    dd_[1] = ((V0)[2] >> 16) | ((V0)[3] & 0xffff0000u);                \
    *(u32x2*)(sl_ + 0 * 64) = dd_;                                     \
    dd_[0] = ((V1)[0] >> 16) | ((V1)[1] & 0xffff0000u);                \
    dd_[1] = ((V1)[2] >> 16) | ((V1)[3] & 0xffff0000u);                \
    *(u32x2*)(sl_ + 1 * 64) = dd_;                                     \
    dd_[0] = ((V2)[0] >> 16) | ((V2)[1] & 0xffff0000u);                \
    dd_[1] = ((V2)[2] >> 16) | ((V2)[3] & 0xffff0000u);                \
    *(u32x2*)(sl_ + 2 * 64) = dd_;                                     \
    dd_[0] = ((V3)[0] >> 16) | ((V3)[1] & 0xffff0000u);                \
    dd_[1] = ((V3)[2] >> 16) | ((V3)[3] & 0xffff0000u);                \
    *(u32x2*)(sl_ + 3 * 64) = dd_;                                     \
    dd_[0] = ((V4)[0] >> 16) | ((V4)[1] & 0xffff0000u);                \
    dd_[1] = ((V4)[2] >> 16) | ((V4)[3] & 0xffff0000u);                \
    *(u32x2*)(sl_ + 4 * 64) = dd_;                                     \
    dd_[0] = ((V5)[0] >> 16) | ((V5)[1] & 0xffff0000u);                \
    dd_[1] = ((V5)[2] >> 16) | ((V5)[3] & 0xffff0000u);                \
    *(u32x2*)(sl_ + 5 * 64) = dd_;                                     \
    dd_[0] = ((V6)[0] >> 16) | ((V6)[1] & 0xffff0000u);                \
    dd_[1] = ((V6)[2] >> 16) | ((V6)[3] & 0xffff0000u);                \
    *(u32x2*)(sl_ + 6 * 64) = dd_;                                     \
    dd_[0] = ((V7)[0] >> 16) | ((V7)[1] & 0xffff0000u);                \
    dd_[1] = ((V7)[2] >> 16) | ((V7)[3] & 0xffff0000u);                \
    *(u32x2*)(sl_ + 7 * 64) = dd_;                                     \
  } while (0)

  for (int t = 0; t < TT; ++t) {
    int par = t & 1;
    unsigned expd = (unsigned)t;

    // =============== chain A ===============
    if (t > 0) {
      const char* an = par ? acqA1 : acqA0;
      u32x4 v0, v1, v2, v3, v4, v5, v6, v7;
      mega_acq(an, v0, v1, v2, v3, v4, v5, v6, v7);
      while ((chk4(v0, expd) | chk4(v1, expd) | chk4(v2, expd) | chk4(v3, expd) |
              chk4(v4, expd) | chk4(v5, expd) | chk4(v6, expd) | chk4(v7, expd)) != 0u)
        mega_acq(an, v0, v1, v2, v3, v4, v5, v6, v7);
      LANDALL(SbufA, v0, v1, v2, v3, v4, v5, v6, v7);
    }
    __syncthreads();   // SbufA complete; also: all waves past MFMA B(t-1)

    {
      f32x4 a0e = {}, a0o = {}, a1e = {}, a1o = {};
      const unsigned short* sb = &SbufA[lane15 * 520 + kslot * 8];
#pragma unroll
      for (int kk = 0; kk < 16; kk += 2) {
        bf16x8 f0 = *(const bf16x8*)(sb + kk * 32);
        bf16x8 f1 = *(const bf16x8*)(sb + (kk + 1) * 32);
        a0e = __builtin_amdgcn_mfma_f32_16x16x32_bf16(Af0[kk],     f0, a0e, 0, 0, 0);
        a1e = __builtin_amdgcn_mfma_f32_16x16x32_bf16(Af1[kk],     f0, a1e, 0, 0, 0);
        a0o = __builtin_amdgcn_mfma_f32_16x16x32_bf16(Af0[kk + 1], f1, a0o, 0, 0, 0);
        a1o = __builtin_amdgcn_mfma_f32_16x16x32_bf16(Af1[kk + 1], f1, a1o, 0, 0, 0);
      }
      float sn[4];
#pragma unroll
      for (int q = 0; q < 4; ++q) {
        float f0 = fast_tanh((a0e[q] + a0o[q]) + bfat(pA0, q));
        float f;
        if (z != 0) {
          float f1 = fast_tanh((a1e[q] + a1o[q]) + bfat(pA1, q));
          f = om_a * f0 + alpha * f1;
        } else f = f0;
        float gval = bfat(pAg, q);
        sn[q] = gval * f + (1.0f - gval) * sprevA[q];
        sprevA[q] = sn[q];
      }
      // publish s_{t+1} (epoch t+1)
      {
        unsigned nxt = (unsigned)(t + 1);
        u32x4 w;
#pragma unroll
        for (int q = 0; q < 4; ++q) w[q] = ((unsigned)f2bf(sn[q]) << 16) | nxt;
        st_coh_b128(par ? pubA0 : pubA1, w);
      }
      // fire-and-forget out + next proj (overlaps chain B's acquire)
      outA += SS;
      { float4 o4 = {sn[0], sn[1], sn[2], sn[3]}; *(float4*)outA = o4; }
      if (t + 1 < TT) {
        ppA += (size_t)BB * 1536;
        pA0 = *(const u32x2*)(ppA);
        pA1 = *(const u32x2*)(ppA + 512);
        pAg = *(const u32x2*)(ppA + 1024);
      }
    }

    // =============== chain B ===============
    if (t > 0) {
      const char* an = par ? acqB1 : acqB0;
      u32x4 v0, v1, v2, v3, v4, v5, v6, v7;
      mega_acq(an, v0, v1, v2, v3, v4, v5, v6, v7);
      while ((chk4(v0, expd) | chk4(v1, expd) | chk4(v2, expd) | chk4(v3, expd) |
              chk4(v4, expd) | chk4(v5, expd) | chk4(v6, expd) | chk4(v7, expd)) != 0u)
        mega_acq(an, v0, v1, v2, v3, v4, v5, v6, v7);
      LANDALL(SbufB, v0, v1, v2, v3, v4, v5, v6, v7);
    }
    __syncthreads();   // SbufB complete; also: all waves past MFMA A(t)

    {
      f32x4 a0e = {}, a0o = {}, a1e = {}, a1o = {};
      const unsigned short* sb = &SbufB[lane15 * 520 + kslot * 8];
#pragma unroll
      for (int kk = 0; kk < 16; kk += 2) {
        bf16x8 f0 = *(const bf16x8*)(sb + kk * 32);
        bf16x8 f1 = *(const bf16x8*)(sb + (kk + 1) * 32);
        a0e = __builtin_amdgcn_mfma_f32_16x16x32_bf16(Af0[kk],     f0, a0e, 0, 0, 0);
        a1e = __builtin_amdgcn_mfma_f32_16x16x32_bf16(Af1[kk],     f0, a1e, 0, 0, 0);
        a0o = __builtin_amdgcn_mfma_f32_16x16x32_bf16(Af0[kk + 1], f1, a0o, 0, 0, 0);
        a1o = __builtin_amdgcn_mfma_f32_16x16x32_bf16(Af1[kk + 1], f1, a1o, 0, 0, 0);
      }
      float sn[4];
#pragma unroll
      for (int q = 0; q < 4; ++q) {
        float f0 = fast_tanh((a0e[q] + a0o[q]) + bfat(pB0, q));
        float f;
        if (z != 0) {
          float f1 = fast_tanh((a1e[q] + a1o[q]) + bfat(pB1, q));
          f = om_a * f0 + alpha * f1;
        } else f = f0;
        float gval = bfat(pBg, q);
        sn[q] = gval * f + (1.0f - gval) * sprevB[q];
        sprevB[q] = sn[q];
      }
      {
        unsigned nxt = (unsigned)(t + 1);
        u32x4 w;
#pragma unroll
        for (int q = 0; q < 4; ++q) w[q] = ((unsigned)f2bf(sn[q]) << 16) | nxt;
        st_coh_b128(par ? pubB0 : pubB1, w);
      }
      outB += SS;
      { float4 o4 = {sn[0], sn[1], sn[2], sn[3]}; *(float4*)outB = o4; }
      if (t + 1 < TT) {
        ppB += (size_t)BB * 1536;
        pB0 = *(const u32x2*)(ppB);
        pB1 = *(const u32x2*)(ppB + 512);
        pBg = *(const u32x2*)(ppB + 1024);
      }
    }
  }
#undef LANDALL
}

// =====================================================================
extern "C" void kernel_launch(void* const* d_in, const int* in_sizes, int n_in,
                              void* d_out, int out_size, void* d_ws, size_t ws_size,
                              hipStream_t stream) {
  const float* x   = (const float*)d_in[0];
  const float* s0  = (const float*)d_in[1];
  const float* A0w = (const float*)d_in[2];
  const float* B0w = (const float*)d_in[3];
  const float* B0b = (const float*)d_in[4];
  const float* A1w = (const float*)d_in[5];
  const float* B1w = (const float*)d_in[6];
  const float* B1b = (const float*)d_in[7];
  const float* Gw  = (const float*)d_in[8];
  const float* Gb  = (const float*)d_in[9];
  const float* alp = (const float*)d_in[10];
  const int*   zp  = (const int*)d_in[11];
  float* out = (float*)d_out;

  char* ws = (char*)d_ws;
  size_t proj_bytes  = (size_t)BB * TT * 1536 * 2;        // 402,653,184
  size_t state_bytes = (size_t)2 * BB * SS * 4;           // 524,288
  unsigned short* proj    = (unsigned short*)(ws);
  unsigned int*   state32 = (unsigned int*)(ws + proj_bytes);

  // zero epoch buffer every launch (replay-safe: epoch 0 never expected)
  hipMemsetAsync(state32, 0, state_bytes, stream);

  proj_kernel<<<dim3(131072 / 64), dim3(256), 0, stream>>>(
      x, B0w, B0b, B1w, B1b, Gw, Gb, proj);

  recur_kernel<<<dim3(32), dim3(256), 0, stream>>>(
      s0, A0w, A1w, proj, alp, zp, state32, out);
}